// Round 6
// baseline (3719.733 us; speedup 1.0000x reference)
//
#include <hip/hip_runtime.h>
#include <hip/hip_fp16.h>

typedef _Float16 f16;
typedef __attribute__((ext_vector_type(8))) _Float16 f16x8;
typedef __attribute__((ext_vector_type(4))) _Float16 f16x4;
typedef __attribute__((ext_vector_type(4))) float f32x4;

#define D_      512
#define NG_     2048
#define B_      64
#define S_      256
#define C_      16
#define M_      (B_*S_)      // 16384

// ---- workspace layout (bytes) ----
#define OFF_X    0ull
#define SZ_X     ((unsigned long long)M_*D_*2)            // x fp16 [16384][512]
#define OFF_G    (OFF_X + SZ_X)
#define SZ_G     ((unsigned long long)M_*NG_*2)           // G2 fp16 [16384][512][4] gate-interleaved
#define OFF_WI   (OFF_G + SZ_G)
#define SZ_WI    ((unsigned long long)NG_*D_*2)           // W_ih fp16
#define OFF_HG   (OFF_WI + SZ_WI)
#define SZ_HG    (2ull*4*16*256*4)                        // h slab dbl-buf [2][4cl][16ch][256 uint]
#define OFF_FH   (OFF_HG + SZ_HG)
#define SZ_FH    ((unsigned long long)B_*D_*4)            // final_h f32 [64][512]
#define OFF_FL   (OFF_FH + SZ_FH)
#define SZ_FL    (64ull*64*4)                             // seq: 64 WGs x 64-uint stride
#define WS_NEED  (OFF_FL + SZ_FL)

__device__ __forceinline__ float sigmoidf_(float x) { return 1.f / (1.f + __expf(-x)); }
__device__ __forceinline__ float tanhf_(float x) {
  float a = fabsf(x);
  float e = __expf(-2.f * a);
  float r = (1.f - e) / (1.f + e);
  return copysignf(r, x);
}

// ---------------- K0: zero the seq flags ----------------
__global__ void k_zero(unsigned* __restrict__ p) {
  for (int i = threadIdx.x; i < 64 * 64; i += 256) p[i] = 0u;
}

// ---------------- K1: embedding gather + sum -> x fp16 ----------------
__global__ void k_embed(const int* __restrict__ seqs, const float* __restrict__ table,
                        f16* __restrict__ x) {
  const int m = blockIdx.x;
  const int t = threadIdx.x;
  const int* idx = seqs + (size_t)m * C_;
  float4 acc = {0.f, 0.f, 0.f, 0.f};
  #pragma unroll
  for (int r = 0; r < C_; ++r) {
    int id = idx[r];  // row VOCAB is all-zero in the provided table
    const float4* row = (const float4*)(table + (size_t)id * D_);
    float4 v = row[t];
    acc.x += v.x; acc.y += v.y; acc.z += v.z; acc.w += v.w;
  }
  f16x4 o;
  o[0] = (f16)acc.x; o[1] = (f16)acc.y; o[2] = (f16)acc.z; o[3] = (f16)acc.w;
  *(f16x4*)(x + (size_t)m * D_ + t * 4) = o;
}

// ---------------- K1b: convert W_ih fp32 -> fp16 ----------------
__global__ void k_cvtw(const float* __restrict__ w, f16* __restrict__ o, int n) {
  int i = blockIdx.x * 256 + threadIdx.x;
  if (i < n) o[i] = (f16)w[i];
}

// ---------------- K2: G2 = x @ W_ih^T, gate-interleaved output ----------------
// grid (32 ntiles, 256 mtiles) x 256 thr: XCD = bid%8 = nt%8 -> each XCD keeps a
// fixed 4-ntile wi slice (256KB) L2-resident. Output layout: G2[m][col][gate],
// col = n&511, gate = n>>9 -> recurrence epilogue reads one f16x4 per chain.
__global__ void k_gemm_ih(const f16* __restrict__ x, const f16* __restrict__ wi,
                          f16* __restrict__ G2) {
  const int nt = blockIdx.x, mt = blockIdx.y;
  const int wid = threadIdx.x >> 6, lane = threadIdx.x & 63;
  const int lr = lane & 15, lq = lane >> 4;
  const int m0 = mt * 64 + wid * 16;
  const int n0 = nt * 64;
  const int gate = nt >> 3;
  const int cbase = (nt & 7) * 64;  // within-gate col base

  f32x4 acc[4] = {{0.f,0.f,0.f,0.f},{0.f,0.f,0.f,0.f},{0.f,0.f,0.f,0.f},{0.f,0.f,0.f,0.f}};
  for (int kt = 0; kt < 16; ++kt) {
    const int k0 = kt * 32 + lq * 8;
    const f16x8 a = *(const f16x8*)(x + (size_t)(m0 + lr) * D_ + k0);
    #pragma unroll
    for (int j = 0; j < 4; ++j) {
      const f16x8 b = *(const f16x8*)(wi + (size_t)(n0 + j * 16 + lr) * D_ + k0);
      acc[j] = __builtin_amdgcn_mfma_f32_16x16x32_f16(a, b, acc[j], 0, 0, 0);
    }
  }
  // D mapping: col = lane&15 (n), row = (lane>>4)*4 + reg (m)
  #pragma unroll
  for (int j = 0; j < 4; ++j)
    #pragma unroll
    for (int rr = 0; rr < 4; ++rr) {
      const int m = m0 + lq * 4 + rr;
      const int col = cbase + j * 16 + lr;
      G2[(size_t)m * NG_ + col * 4 + gate] = (f16)acc[j][rr];
    }
}

// ---------------- K3: LSTM recurrence ----------------
// 64 WGs x 512 thr. cluster cl = bid&3 (16 WGs, 16 chains); rank r = bid>>2 (0..15).
// WG owns 128 W_hh rows ({i,f,g,o} x h-cols [r*32,(r+1)*32)) as persistent VGPR
// B-frags (64 VGPR -> no spill; R4's 128-VGPR version spilled, VGPR_Count=128).
// Sync: per-WG seq word, RELEASE store by tid0 (no RMW serialization). Wave wid
// polls exactly its two producer WGs {2wid, 2wid+1} (wave-uniform ACQUIRE loads),
// then gathers its k-slots immediately -- no barrier between poll and gather.
// Dbl-buf reuse distance 2 is safe: WG reaches its step t+2 slab write only after
// all its waves saw both producer flags >= t+2, and a producer's flag hits t+2
// only after that producer's step-t gather of buffer t&1 completed.
__global__ __launch_bounds__(512, 1) void k_lstm(
    const float* __restrict__ whh, const f16* __restrict__ G2,
    const int* __restrict__ lengths, unsigned* __restrict__ hGu,
    unsigned* __restrict__ seq, float* __restrict__ final_h) {
  const int bid = blockIdx.x;
  const int cl = bid & 3;
  const int r = bid >> 2;          // 0..15
  const int tid = threadIdx.x;
  const int wid = tid >> 6, lane = tid & 63;
  const int lr = lane & 15, lq = lane >> 4;

  __shared__ f16 h_lds[16][522];     // 261 dwords/row; 261%32=5 -> banks spread
  __shared__ float glds[4][32][21];  // [gate][h-col in WG][chain], odd pad -> 2-way reads
  __shared__ int steps_sh;

  // persistent W_hh B-frags: wave wid -> gate (wid>>1), half (wid&1); 16 x f16x8
  const int gi = wid >> 1, jh = wid & 1;
  const int nrow = gi * 512 + r * 32 + jh * 16 + lr;
  f16x8 wfrag[16];
  #pragma unroll
  for (int kt = 0; kt < 16; ++kt) {
    const int k0 = kt * 32 + lq * 8;
    const float* p = whh + (size_t)nrow * D_ + k0;
    f16x8 w;
    #pragma unroll
    for (int e = 0; e < 8; ++e) w[e] = (f16)p[e];
    wfrag[kt] = w;
  }

  for (int i = tid; i < 16 * 522; i += 512) ((f16*)h_lds)[i] = (f16)0.f;

  // epilogue mapping: chain ec = tid>>5, h-col ej = tid&31
  const int ec = tid >> 5;
  const int ej = tid & 31;
  const int b_ec = cl * 16 + ec;
  const int len_ec = lengths[b_ec];

  if (tid == 0) {
    int mx = 0;
    for (int c = 0; c < 16; ++c) mx = max(mx, lengths[cl * 16 + c]);
    steps_sh = mx;
  }
  float cstate = 0.f;
  __syncthreads();
  const int steps = steps_sh;

  // gather mapping: chain gc = tid&15, k-slot gq = tid>>4 (32 slots x 16 f16).
  // wave wid covers gq in [4wid, 4wid+4) -> producers {2wid, 2wid+1} (uniform).
  const int gc = tid & 15;
  const int gq = tid >> 4;
  unsigned* flagA = seq + (cl * 16 + 2 * wid) * 64;
  unsigned* flagB = flagA + 64;
  unsigned* wgflag = seq + (cl * 16 + r) * 64;

  // G fragment prefetch (t = 0)
  const size_t gb = (size_t)b_ec * S_ * NG_ + (size_t)(r * 32 + ej) * 4;
  f16x4 gf = *(const f16x4*)(G2 + gb);

  for (int t = 0; t < steps; ++t) {
    // 1. MFMA: one 16-deep chain (A = h rows 0..15 from LDS)
    f32x4 acc = {0.f, 0.f, 0.f, 0.f};
    #pragma unroll
    for (int kt = 0; kt < 16; ++kt) {
      const f16x8 a = *(const f16x8*)&h_lds[lr][kt * 32 + lq * 8];
      acc = __builtin_amdgcn_mfma_f32_16x16x32_f16(a, wfrag[kt], acc, 0, 0, 0);
    }
    // D: row = chain = lq*4+reg, col = lane&15 -> glds[gate][n_local][chain]
    #pragma unroll
    for (int rr = 0; rr < 4; ++rr)
      glds[gi][jh * 16 + lr][lq * 4 + rr] = acc[rr];
    __syncthreads();  // barrier 1: glds ready

    // 2. epilogue: thread (ec, ej)
    {
      float ig = glds[0][ej][ec] + (float)gf[0];
      float fg = glds[1][ej][ec] + (float)gf[1];
      float gg = glds[2][ej][ec] + (float)gf[2];
      float og = glds[3][ej][ec] + (float)gf[3];
      ig = sigmoidf_(ig); fg = sigmoidf_(fg); og = sigmoidf_(og); gg = tanhf_(gg);
      cstate = fg * cstate + ig * gg;
      const float hv = og * tanhf_(cstate);
      if (t == len_ec - 1) final_h[(size_t)b_ec * D_ + r * 32 + ej] = hv;

      // pack pairs (ej even | ej odd << 16), agent-scope store to slab
      unsigned hb = (unsigned)(unsigned short)__builtin_bit_cast(unsigned short, (f16)hv);
      unsigned other = __shfl_xor(hb, 1);
      if (!(ej & 1)) {
        const size_t sb = (size_t)(t & 1) * 16384 + cl * 4096;
        __hip_atomic_store(&hGu[sb + ec * 256 + r * 16 + (ej >> 1)],
                           hb | (other << 16), __ATOMIC_RELAXED, __HIP_MEMORY_SCOPE_AGENT);
      }
    }

    // 3. prefetch next-step G (latency hides under the store-drain barrier)
    {
      const int tn = min(t + 1, S_ - 1);
      gf = *(const f16x4*)(G2 + gb + (size_t)tn * NG_);
    }
    __syncthreads();  // barrier 2: all waves' slab stores drained (vmcnt 0)

    if (tid == 0)
      __hip_atomic_store(wgflag, (unsigned)(t + 1), __ATOMIC_RELEASE, __HIP_MEMORY_SCOPE_AGENT);

    // 4. poll both producer WGs' seq words (wave-uniform), then gather
    while (__hip_atomic_load(flagA, __ATOMIC_ACQUIRE, __HIP_MEMORY_SCOPE_AGENT)
           < (unsigned)(t + 1))
      __builtin_amdgcn_s_sleep(1);
    while (__hip_atomic_load(flagB, __ATOMIC_ACQUIRE, __HIP_MEMORY_SCOPE_AGENT)
           < (unsigned)(t + 1))
      __builtin_amdgcn_s_sleep(1);
    {
      const size_t base = (size_t)(t & 1) * 16384 + cl * 4096 + gc * 256 + gq * 8;
      unsigned v[8];
      #pragma unroll
      for (int e = 0; e < 8; ++e)
        v[e] = __hip_atomic_load(&hGu[base + e], __ATOMIC_RELAXED, __HIP_MEMORY_SCOPE_AGENT);
      unsigned* dst = (unsigned*)&h_lds[gc][gq * 16];
      #pragma unroll
      for (int e = 0; e < 8; ++e) dst[e] = v[e];
    }
    __syncthreads();  // barrier 3: h(t) complete in LDS for next step
  }
}

// ---------------- K4: out = final_h @ w_out^T + b_out ----------------
__global__ void k_head(const float* __restrict__ fh, const float* __restrict__ wout,
                       const float* __restrict__ bout, float* __restrict__ out) {
  const int b = blockIdx.x;
  const int lane = threadIdx.x;  // 64
  float p0 = 0.f, p1 = 0.f;
  for (int k = lane; k < D_; k += 64) {
    const float h = fh[(size_t)b * D_ + k];
    p0 += h * wout[k];
    p1 += h * wout[D_ + k];
  }
  #pragma unroll
  for (int off = 32; off; off >>= 1) {
    p0 += __shfl_down(p0, off);
    p1 += __shfl_down(p1, off);
  }
  if (lane == 0) {
    out[b * 2 + 0] = p0 + bout[0];
    out[b * 2 + 1] = p1 + bout[1];
  }
}

extern "C" void kernel_launch(void* const* d_in, const int* in_sizes, int n_in,
                              void* d_out, int out_size, void* d_ws, size_t ws_size,
                              hipStream_t stream) {
  const int* seqs = (const int*)d_in[0];
  const int* lengths = (const int*)d_in[1];
  const float* table = (const float*)d_in[2];
  const float* wih = (const float*)d_in[3];
  const float* whh = (const float*)d_in[4];
  const float* wout = (const float*)d_in[5];
  const float* bout = (const float*)d_in[6];
  float* out = (float*)d_out;
  char* ws = (char*)d_ws;
  if (ws_size < WS_NEED) return;

  f16* x = (f16*)(ws + OFF_X);
  f16* G2 = (f16*)(ws + OFF_G);
  f16* wi16 = (f16*)(ws + OFF_WI);
  unsigned* hGu = (unsigned*)(ws + OFF_HG);
  float* fh = (float*)(ws + OFF_FH);
  unsigned* seqf = (unsigned*)(ws + OFF_FL);

  hipLaunchKernelGGL(k_zero, dim3(1), dim3(256), 0, stream, seqf);
  hipLaunchKernelGGL(k_embed, dim3(M_), dim3(128), 0, stream, seqs, table, x);
  hipLaunchKernelGGL(k_cvtw, dim3((NG_ * D_ + 255) / 256), dim3(256), 0, stream,
                     wih, wi16, NG_ * D_);
  hipLaunchKernelGGL(k_gemm_ih, dim3(NG_ / 64, M_ / 64), dim3(256), 0, stream, x, wi16, G2);
  hipLaunchKernelGGL(k_lstm, dim3(64), dim3(512), 0, stream, whh, G2, lengths, hGu, seqf, fh);
  hipLaunchKernelGGL(k_head, dim3(B_), dim3(64), 0, stream, fh, wout, bout, out);
}

// Round 7
// 1825.211 us; speedup vs baseline: 2.0380x; 2.0380x over previous
//
#include <hip/hip_runtime.h>
#include <hip/hip_fp16.h>

typedef _Float16 f16;
typedef __attribute__((ext_vector_type(8))) _Float16 f16x8;
typedef __attribute__((ext_vector_type(4))) _Float16 f16x4;
typedef __attribute__((ext_vector_type(4))) float f32x4;

#define D_      512
#define NG_     2048
#define B_      64
#define S_      256
#define C_      16
#define M_      (B_*S_)      // 16384

// ---- workspace layout (bytes) ----
#define OFF_X    0ull
#define SZ_X     ((unsigned long long)M_*D_*2)            // x fp16 [16384][512]
#define OFF_G    (OFF_X + SZ_X)
#define SZ_G     ((unsigned long long)M_*NG_*2)           // G2 fp16 [16384][512][4] gate-interleaved
#define OFF_WI   (OFF_G + SZ_G)
#define SZ_WI    ((unsigned long long)NG_*D_*2)           // W_ih fp16
#define OFF_HG   (OFF_WI + SZ_WI)
#define SZ_HG    (2ull*4*16*256*4)                        // h slab dbl-buf [2][4cl][16ch][256 uint]
#define OFF_FH   (OFF_HG + SZ_HG)
#define SZ_FH    ((unsigned long long)B_*D_*4)            // final_h f32 [64][512]
#define OFF_FL   (OFF_FH + SZ_FH)
#define SZ_FL    (64ull*64*4)                             // seq: 64 WGs x 64-uint stride
#define WS_NEED  (OFF_FL + SZ_FL)

__device__ __forceinline__ float sigmoidf_(float x) { return 1.f / (1.f + __expf(-x)); }
__device__ __forceinline__ float tanhf_(float x) {
  float a = fabsf(x);
  float e = __expf(-2.f * a);
  float r = (1.f - e) / (1.f + e);
  return copysignf(r, x);
}

// ---------------- K0: zero the seq flags ----------------
__global__ void k_zero(unsigned* __restrict__ p) {
  for (int i = threadIdx.x; i < 64 * 64; i += 256) p[i] = 0u;
}

// ---------------- K1: embedding gather + sum -> x fp16 ----------------
__global__ void k_embed(const int* __restrict__ seqs, const float* __restrict__ table,
                        f16* __restrict__ x) {
  const int m = blockIdx.x;
  const int t = threadIdx.x;
  const int* idx = seqs + (size_t)m * C_;
  float4 acc = {0.f, 0.f, 0.f, 0.f};
  #pragma unroll
  for (int r = 0; r < C_; ++r) {
    int id = idx[r];  // row VOCAB is all-zero in the provided table
    const float4* row = (const float4*)(table + (size_t)id * D_);
    float4 v = row[t];
    acc.x += v.x; acc.y += v.y; acc.z += v.z; acc.w += v.w;
  }
  f16x4 o;
  o[0] = (f16)acc.x; o[1] = (f16)acc.y; o[2] = (f16)acc.z; o[3] = (f16)acc.w;
  *(f16x4*)(x + (size_t)m * D_ + t * 4) = o;
}

// ---------------- K1b: convert W_ih fp32 -> fp16 ----------------
__global__ void k_cvtw(const float* __restrict__ w, f16* __restrict__ o, int n) {
  int i = blockIdx.x * 256 + threadIdx.x;
  if (i < n) o[i] = (f16)w[i];
}

// ---------------- K2: G2 = x @ W_ih^T, gate-interleaved output ----------------
// grid (32 ntiles, 256 mtiles) x 256 thr: XCD = bid%8 = nt%8 -> each XCD keeps a
// fixed 4-ntile wi slice (256KB) L2-resident. Output layout: G2[m][col][gate],
// col = n&511, gate = n>>9 -> recurrence epilogue reads one f16x4 per chain.
__global__ void k_gemm_ih(const f16* __restrict__ x, const f16* __restrict__ wi,
                          f16* __restrict__ G2) {
  const int nt = blockIdx.x, mt = blockIdx.y;
  const int wid = threadIdx.x >> 6, lane = threadIdx.x & 63;
  const int lr = lane & 15, lq = lane >> 4;
  const int m0 = mt * 64 + wid * 16;
  const int n0 = nt * 64;
  const int gate = nt >> 3;
  const int cbase = (nt & 7) * 64;  // within-gate col base

  f32x4 acc[4] = {{0.f,0.f,0.f,0.f},{0.f,0.f,0.f,0.f},{0.f,0.f,0.f,0.f},{0.f,0.f,0.f,0.f}};
  for (int kt = 0; kt < 16; ++kt) {
    const int k0 = kt * 32 + lq * 8;
    const f16x8 a = *(const f16x8*)(x + (size_t)(m0 + lr) * D_ + k0);
    #pragma unroll
    for (int j = 0; j < 4; ++j) {
      const f16x8 b = *(const f16x8*)(wi + (size_t)(n0 + j * 16 + lr) * D_ + k0);
      acc[j] = __builtin_amdgcn_mfma_f32_16x16x32_f16(a, b, acc[j], 0, 0, 0);
    }
  }
  // D mapping: col = lane&15 (n), row = (lane>>4)*4 + reg (m)
  #pragma unroll
  for (int j = 0; j < 4; ++j)
    #pragma unroll
    for (int rr = 0; rr < 4; ++rr) {
      const int m = m0 + lq * 4 + rr;
      const int col = cbase + j * 16 + lr;
      G2[(size_t)m * NG_ + col * 4 + gate] = (f16)acc[j][rr];
    }
}

// ---------------- K3: LSTM recurrence ----------------
// 64 WGs x 512 thr. cluster cl = bid&3 (16 WGs, 16 chains); rank r = bid>>2 (0..15).
// WG owns 128 W_hh rows ({i,f,g,o} x h-cols [r*32,(r+1)*32)) as persistent VGPR
// B-frags (64 VGPR, no spill). Per-WG seq flag, RELEASE store (no RMW).
// POLL DISCIPLINE (R6 lesson): ONLY WAVE 0 polls -- R6's 8-waves-x-2-flags spin
// produced 57.7 GB of LLC refetch traffic (800x over-fetch) that queued ahead of
// the exchange data itself. Wave 0: each lane loads flag[lane&15] (one vector
// instr, 16 LLC lines), __all ballot, s_sleep(2) backoff; other waves wait at
// the barrier. Spin requests cut ~32x.
// Dbl-buf reuse distance 2 is safe: WG reaches its step t+2 slab write only after
// wave0 saw ALL cluster flags >= t+2; WG q's flag hits t+2 only after q's step-t
// gather of buffer t&1 completed.
__global__ __launch_bounds__(512, 1) void k_lstm(
    const float* __restrict__ whh, const f16* __restrict__ G2,
    const int* __restrict__ lengths, unsigned* __restrict__ hGu,
    unsigned* __restrict__ seq, float* __restrict__ final_h) {
  const int bid = blockIdx.x;
  const int cl = bid & 3;
  const int r = bid >> 2;          // 0..15
  const int tid = threadIdx.x;
  const int wid = tid >> 6, lane = tid & 63;
  const int lr = lane & 15, lq = lane >> 4;

  __shared__ f16 h_lds[16][522];     // 261 dwords/row; 261%32=5 -> banks spread
  __shared__ float glds[4][32][21];  // [gate][h-col in WG][chain], odd pad -> 2-way reads
  __shared__ int steps_sh;

  // persistent W_hh B-frags: wave wid -> gate (wid>>1), half (wid&1); 16 x f16x8
  const int gi = wid >> 1, jh = wid & 1;
  const int nrow = gi * 512 + r * 32 + jh * 16 + lr;
  f16x8 wfrag[16];
  #pragma unroll
  for (int kt = 0; kt < 16; ++kt) {
    const int k0 = kt * 32 + lq * 8;
    const float* p = whh + (size_t)nrow * D_ + k0;
    f16x8 w;
    #pragma unroll
    for (int e = 0; e < 8; ++e) w[e] = (f16)p[e];
    wfrag[kt] = w;
  }

  for (int i = tid; i < 16 * 522; i += 512) ((f16*)h_lds)[i] = (f16)0.f;

  // epilogue mapping: chain ec = tid>>5, h-col ej = tid&31
  const int ec = tid >> 5;
  const int ej = tid & 31;
  const int b_ec = cl * 16 + ec;
  const int len_ec = lengths[b_ec];

  if (tid == 0) {
    int mx = 0;
    for (int c = 0; c < 16; ++c) mx = max(mx, lengths[cl * 16 + c]);
    steps_sh = mx;
  }
  float cstate = 0.f;
  __syncthreads();
  const int steps = steps_sh;

  // gather mapping: chain gc = tid&15, k-slot gq = tid>>4 (32 slots x 16 f16)
  const int gc = tid & 15;
  const int gq = tid >> 4;
  unsigned* wgflag = seq + (cl * 16 + r) * 64;
  const unsigned* pollflag = seq + (cl * 16 + (lane & 15)) * 64;  // wave0 poll addr

  // G fragment prefetch (t = 0)
  const size_t gb = (size_t)b_ec * S_ * NG_ + (size_t)(r * 32 + ej) * 4;
  f16x4 gf = *(const f16x4*)(G2 + gb);

  for (int t = 0; t < steps; ++t) {
    // 1. MFMA: one 16-deep chain (A = h rows 0..15 from LDS)
    f32x4 acc = {0.f, 0.f, 0.f, 0.f};
    #pragma unroll
    for (int kt = 0; kt < 16; ++kt) {
      const f16x8 a = *(const f16x8*)&h_lds[lr][kt * 32 + lq * 8];
      acc = __builtin_amdgcn_mfma_f32_16x16x32_f16(a, wfrag[kt], acc, 0, 0, 0);
    }
    // D: row = chain = lq*4+reg, col = lane&15 -> glds[gate][n_local][chain]
    #pragma unroll
    for (int rr = 0; rr < 4; ++rr)
      glds[gi][jh * 16 + lr][lq * 4 + rr] = acc[rr];
    __syncthreads();  // barrier 1: glds ready

    // 2. epilogue: thread (ec, ej)
    {
      float ig = glds[0][ej][ec] + (float)gf[0];
      float fg = glds[1][ej][ec] + (float)gf[1];
      float gg = glds[2][ej][ec] + (float)gf[2];
      float og = glds[3][ej][ec] + (float)gf[3];
      ig = sigmoidf_(ig); fg = sigmoidf_(fg); og = sigmoidf_(og); gg = tanhf_(gg);
      cstate = fg * cstate + ig * gg;
      const float hv = og * tanhf_(cstate);
      if (t == len_ec - 1) final_h[(size_t)b_ec * D_ + r * 32 + ej] = hv;

      // pack pairs (ej even | ej odd << 16), agent-scope store to slab
      unsigned hb = (unsigned)(unsigned short)__builtin_bit_cast(unsigned short, (f16)hv);
      unsigned other = __shfl_xor(hb, 1);
      if (!(ej & 1)) {
        const size_t sb = (size_t)(t & 1) * 16384 + cl * 4096;
        __hip_atomic_store(&hGu[sb + ec * 256 + r * 16 + (ej >> 1)],
                           hb | (other << 16), __ATOMIC_RELAXED, __HIP_MEMORY_SCOPE_AGENT);
      }
    }

    // 3. prefetch next-step G (latency hides under the store-drain barrier)
    {
      const int tn = min(t + 1, S_ - 1);
      gf = *(const f16x4*)(G2 + gb + (size_t)tn * NG_);
    }
    __syncthreads();  // barrier 2: all waves' slab stores drained (vmcnt 0)

    if (tid == 0)
      __hip_atomic_store(wgflag, (unsigned)(t + 1), __ATOMIC_RELEASE, __HIP_MEMORY_SCOPE_AGENT);

    // 4. wave 0 ONLY polls all 16 cluster flags (lane i -> flag[i&15]); others
    //    wait at the barrier. s_sleep(2) backoff between rounds.
    if (wid == 0) {
      const unsigned tgt = (unsigned)(t + 1);
      for (;;) {
        unsigned v = __hip_atomic_load(pollflag, __ATOMIC_ACQUIRE, __HIP_MEMORY_SCOPE_AGENT);
        if (__all(v >= tgt)) break;
        __builtin_amdgcn_s_sleep(2);
      }
    }
    __syncthreads();  // barrier 3: all producer flags observed

    // 5. gather full cluster h -> LDS (relaxed agent loads from LLC slab)
    {
      const size_t base = (size_t)(t & 1) * 16384 + cl * 4096 + gc * 256 + gq * 8;
      unsigned v[8];
      #pragma unroll
      for (int e = 0; e < 8; ++e)
        v[e] = __hip_atomic_load(&hGu[base + e], __ATOMIC_RELAXED, __HIP_MEMORY_SCOPE_AGENT);
      unsigned* dst = (unsigned*)&h_lds[gc][gq * 16];
      #pragma unroll
      for (int e = 0; e < 8; ++e) dst[e] = v[e];
    }
    __syncthreads();  // barrier 4: h(t) complete in LDS for next step
  }
}

// ---------------- K4: out = final_h @ w_out^T + b_out ----------------
__global__ void k_head(const float* __restrict__ fh, const float* __restrict__ wout,
                       const float* __restrict__ bout, float* __restrict__ out) {
  const int b = blockIdx.x;
  const int lane = threadIdx.x;  // 64
  float p0 = 0.f, p1 = 0.f;
  for (int k = lane; k < D_; k += 64) {
    const float h = fh[(size_t)b * D_ + k];
    p0 += h * wout[k];
    p1 += h * wout[D_ + k];
  }
  #pragma unroll
  for (int off = 32; off; off >>= 1) {
    p0 += __shfl_down(p0, off);
    p1 += __shfl_down(p1, off);
  }
  if (lane == 0) {
    out[b * 2 + 0] = p0 + bout[0];
    out[b * 2 + 1] = p1 + bout[1];
  }
}

extern "C" void kernel_launch(void* const* d_in, const int* in_sizes, int n_in,
                              void* d_out, int out_size, void* d_ws, size_t ws_size,
                              hipStream_t stream) {
  const int* seqs = (const int*)d_in[0];
  const int* lengths = (const int*)d_in[1];
  const float* table = (const float*)d_in[2];
  const float* wih = (const float*)d_in[3];
  const float* whh = (const float*)d_in[4];
  const float* wout = (const float*)d_in[5];
  const float* bout = (const float*)d_in[6];
  float* out = (float*)d_out;
  char* ws = (char*)d_ws;
  if (ws_size < WS_NEED) return;

  f16* x = (f16*)(ws + OFF_X);
  f16* G2 = (f16*)(ws + OFF_G);
  f16* wi16 = (f16*)(ws + OFF_WI);
  unsigned* hGu = (unsigned*)(ws + OFF_HG);
  float* fh = (float*)(ws + OFF_FH);
  unsigned* seqf = (unsigned*)(ws + OFF_FL);

  hipLaunchKernelGGL(k_zero, dim3(1), dim3(256), 0, stream, seqf);
  hipLaunchKernelGGL(k_embed, dim3(M_), dim3(128), 0, stream, seqs, table, x);
  hipLaunchKernelGGL(k_cvtw, dim3((NG_ * D_ + 255) / 256), dim3(256), 0, stream,
                     wih, wi16, NG_ * D_);
  hipLaunchKernelGGL(k_gemm_ih, dim3(NG_ / 64, M_ / 64), dim3(256), 0, stream, x, wi16, G2);
  hipLaunchKernelGGL(k_lstm, dim3(64), dim3(512), 0, stream, whh, G2, lengths, hGu, seqf, fh);
  hipLaunchKernelGGL(k_head, dim3(B_), dim3(64), 0, stream, fh, wout, bout, out);
}